// Round 1
// baseline (246.309 us; speedup 1.0000x reference)
//
#include <hip/hip_runtime.h>
#include <math.h>

#define NFB  512     // B = nf*ns
#define NMEM 30
#define PIX  1024    // 32*32
#define EPSF 1e-5f

typedef _Float16 half8_t __attribute__((ext_vector_type(8)));
typedef _Float16 half4_t __attribute__((ext_vector_type(4)));
typedef float float4_t __attribute__((ext_vector_type(4)));

// workspace layout (byte offsets):
// (x2h region retained but unused)
// w2rep (f16, 3*64*192)      @ 13,631,488+73,728 region unchanged
#define OFF_W2R   13631488
#define OFF_W3R   13705216
#define OFF_WR1   13778944
#define OFF_WSUM1 13791232

// ---------------------------------------------------------------------------
// k_prep: all weight repacks in one launch. (unchanged)
// ---------------------------------------------------------------------------
__global__ __launch_bounds__(256) void k_prep(
    const float* __restrict__ c1w, const float* __restrict__ c2w,
    const float* __restrict__ c3w, _Float16* __restrict__ w2rep,
    _Float16* __restrict__ w3rep, _Float16* __restrict__ wr1,
    float* __restrict__ wsum1)
{
  int i = blockIdx.x * 256 + threadIdx.x;
  if (i < 36864) {
    int kr = i / 12288, rem = i - kr * 12288;
    int oc = rem / 192, k = rem - oc * 192;
    int kc = k >> 6, ci = k & 63;
    w2rep[i] = (_Float16)c2w[((oc * 64 + ci) * 3 + kr) * 3 + kc];
  } else if (i < 73728) {
    int j = i - 36864;
    int kr = j / 12288, rem = j - kr * 12288;
    int oc = rem / 192, k = rem - oc * 192;
    int kc = k >> 6, ci = k & 63;
    w3rep[j] = (_Float16)c3w[((oc * 64 + ci) * 3 + kr) * 3 + kc];
  } else if (i < 79872) {
    int j = i - 73728;
    int kr = j / 2048, rem = j - kr * 2048;
    int oc = rem >> 5, k = rem & 31;
    int kc = k >> 3, ci = k & 7;
    _Float16 v = (_Float16)0.f;
    if (kc < 3 && ci < 6)
      v = (_Float16)c1w[((oc * 14 + (2 + ci)) * 3 + kr) * 3 + kc];
    wr1[j] = v;
  } else if (i < 80384) {
    int j = i - 79872;
    int oc = j >> 3, u = j & 7;
    const int uch[8] = {0, 1, 8, 9, 10, 11, 12, 13};
    const float* wp = c1w + (oc * 14 + uch[u]) * 9;
    float s = 0.f;
    #pragma unroll
    for (int k = 0; k < 9; ++k) s += wp[k];
    wsum1[j] = s;
  }
}

// ---------------------------------------------------------------------------
// k_mega: whole per-b pipeline. 512 blocks x 256 threads, 2 blocks/CU.
// LDS plan (bytes):
//   IMG [0, 16448)      1028 px * 8 halves
//   X1  [16448, 51008)  240 px * 72 halves
//   X2S [0, 29952)      208 px * 72 halves (conv2 out via registers; IMG+X1 dead)
//   X3  [29952, 55296)  176 px * 72 halves
// ---------------------------------------------------------------------------
__global__ __launch_bounds__(256, 2) void k_mega(
    const float* __restrict__ ts, const float* __restrict__ ptm,
    const float* __restrict__ pmt, const float* __restrict__ piou,
    const int* __restrict__ mask,
    const _Float16* __restrict__ wr1, const float* __restrict__ wsum1,
    const float* __restrict__ c1b, const float* __restrict__ g1,
    const float* __restrict__ b1, const float* __restrict__ m1,
    const float* __restrict__ v1,
    const _Float16* __restrict__ w2rep,
    const float* __restrict__ c2b, const float* __restrict__ g2,
    const float* __restrict__ b2, const float* __restrict__ m2,
    const float* __restrict__ v2,
    const _Float16* __restrict__ w3rep,
    const float* __restrict__ c3b, const float* __restrict__ g3,
    const float* __restrict__ b3, const float* __restrict__ m3,
    const float* __restrict__ v3,
    const float* __restrict__ c4w, const float* __restrict__ c4b,
    float* __restrict__ out)
{
  __shared__ __align__(16) char s_buf[55296];
  __shared__ float s_wm[NMEM], s_wo[NMEM], s_pmax[NMEM];
  __shared__ float s_red[4], s_scal[12], s_cnt[4];
  __shared__ float s_w4[576];   // [k][ci]

  const int b = blockIdx.x, t = threadIdx.x;
  const int lane = t & 63, wave = t >> 6;
  const int n16 = lane & 15, q = lane >> 4;
  _Float16* const IMG = (_Float16*)s_buf;
  _Float16* const X1  = (_Float16*)(s_buf + 16448);
  _Float16* const X2S = (_Float16*)s_buf;
  _Float16* const X3  = (_Float16*)(s_buf + 29952);

  // ======== stage A: stats ========
  // conv4 weights -> LDS (no dependency; hide early)
  for (int i = t; i < 576; i += 256) {
    int ci = i / 9, k = i - ci * 9;
    s_w4[k * 64 + ci] = c4w[i];
  }
  // mask weights + counts (t0)
  if (t == 0) {
    float cum = 0.f, cm = 0.f, cg = 0.f, co = 0.f;
    for (int m = 0; m < NMEM; ++m) {
      float f  = (mask[b * NMEM + m] != 0) ? 1.f : 0.f;
      float gg = (cum < 15.f) ? f : 0.f;
      float oo = f - gg;
      cum += f;
      s_wm[m] = f; s_wo[m] = oo;
      cm += f; cg += gg; co += oo;
    }
    s_cnt[0] = cm; s_cnt[1] = cg; s_cnt[2] = co;
  }
  // per-memory spatial max of ptm: issue ALL loads up front (deep MLP),
  // reduce afterwards. One wave per memory, strided.
  {
    float4 u[8][4];
    const float* pb = ptm + (size_t)b * NMEM * PIX + lane * 4;
    #pragma unroll
    for (int k = 0; k < 8; ++k) {
      int m = wave + 4 * k;
      if (m < NMEM) {
        const float* p = pb + (size_t)m * PIX;
        #pragma unroll
        for (int j = 0; j < 4; ++j) u[k][j] = *(const float4*)(p + j * 256);
      }
    }
    #pragma unroll
    for (int k = 0; k < 8; ++k) {
      int m = wave + 4 * k;
      if (m < NMEM) {
        float4 v0 = u[k][0], v1_ = u[k][1], v2_ = u[k][2], v3_ = u[k][3];
        float mx = fmaxf(fmaxf(fmaxf(v0.x, v0.y), fmaxf(v0.z, v0.w)),
                         fmaxf(fmaxf(v1_.x, v1_.y), fmaxf(v1_.z, v1_.w)));
        mx = fmaxf(mx, fmaxf(fmaxf(fmaxf(v2_.x, v2_.y), fmaxf(v2_.z, v2_.w)),
                             fmaxf(fmaxf(v3_.x, v3_.y), fmaxf(v3_.z, v3_.w))));
        #pragma unroll
        for (int off = 32; off > 0; off >>= 1)
          mx = fmaxf(mx, __shfl_down(mx, off, 64));
        if (lane == 0) s_pmax[m] = mx;
      }
    }
  }
  // ts max
  {
    float4 v = ((const float4*)(ts + (size_t)b * PIX))[t];
    float mx = fmaxf(fmaxf(v.x, v.y), fmaxf(v.z, v.w));
    #pragma unroll
    for (int off = 32; off > 0; off >>= 1)
      mx = fmaxf(mx, __shfl_down(mx, off, 64));
    if (lane == 0) s_red[wave] = mx;
  }
  __syncthreads();
  // scalar stats (t0) — others proceed straight into pmt loop (no s_scal use)
  if (t == 0) {
    float maxts = fmaxf(fmaxf(s_red[0], s_red[1]), fmaxf(s_red[2], s_red[3]));
    float sm = 0, sm2 = 0, sg = 0, sg2 = 0, so = 0, so2 = 0;
    for (int m = 0; m < NMEM; ++m) {
      float x = s_pmax[m];
      float gg = s_wm[m] - s_wo[m];
      sm += s_wm[m] * x;  sm2 += s_wm[m] * x * x;
      sg += gg * x;       sg2 += gg * x * x;
      so += s_wo[m] * x;  so2 += s_wo[m] * x * x;
    }
    float cm = s_cnt[0], cg = s_cnt[1], co = s_cnt[2];
    float a = sm / cm, g = sg / cg, o = so / co;
    s_scal[0] = maxts; s_scal[1] = piou[b];
    s_scal[2] = a; s_scal[3] = sqrtf(fmaxf(sm2 / cm - a * a, 0.f));
    s_scal[4] = g; s_scal[5] = sqrtf(fmaxf(sg2 / cg - g * g, 0.f));
    s_scal[6] = o; s_scal[7] = sqrtf(fmaxf(so2 / co - o * o, 0.f));
  }
  // per-pixel pmt stats -> IMG. Issue all 30 float4 loads first (deep MLP).
  {
    const float cm = s_cnt[0], co = s_cnt[2];
    const int p0 = t * 4;
    const float* pb = pmt + (size_t)b * NMEM * PIX + p0;
    float4 va[15], vb[15];
    #pragma unroll
    for (int j = 0; j < 15; ++j) va[j] = *(const float4*)(pb + (size_t)j * PIX);
    #pragma unroll
    for (int j = 0; j < 15; ++j) vb[j] = *(const float4*)(pb + (size_t)(15 + j) * PIX);
    float sA[4] = {0,0,0,0}, qA[4] = {0,0,0,0};
    float sG[4] = {0,0,0,0}, qG[4] = {0,0,0,0};
    float sO[4] = {0,0,0,0}, qO[4] = {0,0,0,0};
    #pragma unroll
    for (int j = 0; j < 15; ++j) {
      float wm = s_wm[j], wo = s_wo[j];
      float xv[4] = {va[j].x, va[j].y, va[j].z, va[j].w};
      #pragma unroll
      for (int k = 0; k < 4; ++k) {
        float x = xv[k];
        sA[k] = fmaf(wm, x, sA[k]); qA[k] = fmaf(wm * x, x, qA[k]);
        sO[k] = fmaf(wo, x, sO[k]); qO[k] = fmaf(wo * x, x, qO[k]);
        sG[k] += x; qG[k] = fmaf(x, x, qG[k]);
      }
    }
    #pragma unroll
    for (int j = 0; j < 15; ++j) {
      float wm = s_wm[15 + j], wo = s_wo[15 + j];
      float xv[4] = {vb[j].x, vb[j].y, vb[j].z, vb[j].w};
      #pragma unroll
      for (int k = 0; k < 4; ++k) {
        float x = xv[k];
        sA[k] = fmaf(wm, x, sA[k]); qA[k] = fmaf(wm * x, x, qA[k]);
        sO[k] = fmaf(wo, x, sO[k]); qO[k] = fmaf(wo * x, x, qO[k]);
      }
    }
    half8_t* ob = (half8_t*)(IMG) + p0;
    #pragma unroll
    for (int j = 0; j < 4; ++j) {
      float m0 = sA[j] / cm;   float d0 = sqrtf(fmaxf(qA[j] / cm - m0 * m0, 0.f));
      float m1_ = sG[j] / 15.f; float d1 = sqrtf(fmaxf(qG[j] / 15.f - m1_ * m1_, 0.f));
      float m2_ = sO[j] / co;   float d2 = sqrtf(fmaxf(qO[j] / co - m2_ * m2_, 0.f));
      half8_t v;
      v[0] = (_Float16)m0;  v[1] = (_Float16)d0;
      v[2] = (_Float16)m1_; v[3] = (_Float16)d1;
      v[4] = (_Float16)m2_; v[5] = (_Float16)d2;
      v[6] = (_Float16)0.f; v[7] = (_Float16)0.f;
      ob[j] = v;
    }
    if (t < 4) {   // zero the 4 pad pixels (1024..1027)
      half8_t z = {(_Float16)0.f,(_Float16)0.f,(_Float16)0.f,(_Float16)0.f,
                   (_Float16)0.f,(_Float16)0.f,(_Float16)0.f,(_Float16)0.f};
      ((half8_t*)IMG)[1024 + t] = z;
    }
  }
  __syncthreads();

  // ======== conv1 (MFMA) + BN + ReLU + 2x2 maxpool -> X1 (LDS, stride 72) ====
  {
    const int ocA = wave * 16 + n16;
    half8_t af[3];
    #pragma unroll
    for (int kr = 0; kr < 3; ++kr)
      af[kr] = *(const half8_t*)(wr1 + (kr * 64 + ocA) * 32 + q * 8);
    const int oc0 = wave * 16 + q * 4;
    float scv[4], shv[4], cst[4];
    #pragma unroll
    for (int rg = 0; rg < 4; ++rg) {
      int oc = oc0 + rg;
      float s = g1[oc] * rsqrtf(v1[oc] + EPSF);
      scv[rg] = s;
      shv[rg] = (c1b[oc] - m1[oc]) * s + b1[oc];
      float c = 0.f;
      #pragma unroll
      for (int u = 0; u < 8; ++u) c = fmaf(wsum1[oc * 8 + u], s_scal[u], c);
      cst[rg] = c;
    }
    #pragma unroll 1
    for (int pr = 0; pr < 15; ++pr) {
      const int r0 = pr * 2;
      float4_t acc[2][2];
      #pragma unroll
      for (int row = 0; row < 2; ++row)
        #pragma unroll
        for (int tt = 0; tt < 2; ++tt)
          acc[row][tt] = (float4_t){0.f, 0.f, 0.f, 0.f};
      #pragma unroll
      for (int row = 0; row < 2; ++row) {
        #pragma unroll
        for (int kr = 0; kr < 3; ++kr) {
          const int ip = (r0 + row + kr) * 32 + n16 + q;
          #pragma unroll
          for (int tt = 0; tt < 2; ++tt) {
            half8_t bf = *(const half8_t*)(IMG + (ip + tt * 16) * 8);
            acc[row][tt] = __builtin_amdgcn_mfma_f32_16x16x32_f16(
                af[kr], bf, acc[row][tt], 0, 0, 0);
          }
        }
      }
      #pragma unroll
      for (int tt = 0; tt < 2; ++tt) {
        float mm[4];
        #pragma unroll
        for (int j = 0; j < 4; ++j) {
          float m = fmaxf(acc[0][tt][j], acc[1][tt][j]);
          mm[j] = fmaxf(m, __shfl_xor(m, 1, 64));
        }
        if ((n16 & 1) == 0) {
          int pc = tt * 8 + (n16 >> 1);
          half4_t vv;
          if (pc < 15) {
            #pragma unroll
            for (int rg = 0; rg < 4; ++rg)
              vv[rg] = (_Float16)fmaxf(scv[rg] * (mm[rg] + cst[rg]) + shv[rg], 0.f);
          } else {
            vv[0] = (_Float16)0.f; vv[1] = (_Float16)0.f;
            vv[2] = (_Float16)0.f; vv[3] = (_Float16)0.f;
          }
          *(half4_t*)(X1 + (pr * 16 + pc) * 72 + oc0) = vv;
        }
      }
    }
  }
  __syncthreads();

  // ======== conv2 (MFMA): X1(LDS) -> registers -> X2S(LDS) ========
  {
    int base72[11];
    #pragma unroll
    for (int nt = 0; nt < 11; ++nt) {
      int p = nt * 16 + n16;
      int pe = (p < 169) ? p : 168;
      int r = pe / 13, c = pe - r * 13;
      base72[nt] = (r * 16 + c) * 72;
    }
    float4_t acc[11];
    #pragma unroll
    for (int nt = 0; nt < 11; ++nt) acc[nt] = (float4_t){0.f, 0.f, 0.f, 0.f};
    const int ocA = wave * 16 + n16;
    // hoist all weight fragments (3 kr x 6 ks) so the MFMA loop has no
    // global-load stalls mid-stream
    half8_t af[3][6];
    #pragma unroll
    for (int kr = 0; kr < 3; ++kr) {
      const half8_t* wp = (const half8_t*)(w2rep + (size_t)(kr * 64 + ocA) * 192 + q * 8);
      #pragma unroll
      for (int ks = 0; ks < 6; ++ks) af[kr][ks] = wp[ks * 4];
    }
    #pragma unroll 1
    for (int kr = 0; kr < 3; ++kr) {
      const int krbase = kr * (16 * 72);
      #pragma unroll
      for (int ks = 0; ks < 6; ++ks) {
        const int k0 = ks * 32 + q * 8;
        const int kadd = krbase + (k0 >> 6) * 72 + (k0 & 63);
        #pragma unroll
        for (int nt = 0; nt < 11; ++nt) {
          half8_t bf = *(const half8_t*)(X1 + base72[nt] + kadd);
          acc[nt] = __builtin_amdgcn_mfma_f32_16x16x32_f16(af[kr][ks], bf, acc[nt], 0, 0, 0);
        }
      }
    }
    const int ocb = wave * 16 + q * 4;
    float scv[4], shv[4];
    #pragma unroll
    for (int rg = 0; rg < 4; ++rg) {
      int o = ocb + rg;
      float s = g2[o] * rsqrtf(v2[o] + EPSF);
      scv[rg] = s;
      shv[rg] = (c2b[o] - m2[o]) * s + b2[o];
    }
    // BN+ReLU into registers; carry across the barrier instead of a global
    // round-trip through x2h
    half4_t vout[11];
    #pragma unroll
    for (int nt = 0; nt < 11; ++nt) {
      #pragma unroll
      for (int rg = 0; rg < 4; ++rg)
        vout[nt][rg] = (_Float16)fmaxf(acc[nt][rg] * scv[rg] + shv[rg], 0.f);
    }
    __syncthreads();   // all waves done reading X1/IMG; X2S region now free
    #pragma unroll
    for (int nt = 0; nt < 11; ++nt) {
      int p = nt * 16 + n16;
      if (p < 169) {
        int r = p / 13, c = p - r * 13;
        *(half4_t*)(X2S + (r * 16 + c) * 72 + ocb) = vout[nt];
      }
    }
  }
  __syncthreads();

  // ======== conv3 (MFMA): X2S -> X3 (LDS) ========
  {
    int base72[8];
    #pragma unroll
    for (int nt = 0; nt < 8; ++nt) {
      int p = nt * 16 + n16;
      int pe = (p < 121) ? p : 120;
      int r = pe / 11, c = pe - r * 11;
      base72[nt] = (r * 16 + c) * 72;
    }
    float4_t acc[8];
    #pragma unroll
    for (int nt = 0; nt < 8; ++nt) acc[nt] = (float4_t){0.f, 0.f, 0.f, 0.f};
    const int ocA = wave * 16 + n16;
    half8_t af[3][6];
    #pragma unroll
    for (int kr = 0; kr < 3; ++kr) {
      const half8_t* wp = (const half8_t*)(w3rep + (size_t)(kr * 64 + ocA) * 192 + q * 8);
      #pragma unroll
      for (int ks = 0; ks < 6; ++ks) af[kr][ks] = wp[ks * 4];
    }
    #pragma unroll 1
    for (int kr = 0; kr < 3; ++kr) {
      const int krbase = kr * (16 * 72);
      #pragma unroll
      for (int ks = 0; ks < 6; ++ks) {
        const int k0 = ks * 32 + q * 8;
        const int kadd = krbase + (k0 >> 6) * 72 + (k0 & 63);
        #pragma unroll
        for (int nt = 0; nt < 8; ++nt) {
          half8_t bf = *(const half8_t*)(X2S + base72[nt] + kadd);
          acc[nt] = __builtin_amdgcn_mfma_f32_16x16x32_f16(af[kr][ks], bf, acc[nt], 0, 0, 0);
        }
      }
    }
    const int ocb = wave * 16 + q * 4;
    float scv[4], shv[4];
    #pragma unroll
    for (int rg = 0; rg < 4; ++rg) {
      int o = ocb + rg;
      float s = g3[o] * rsqrtf(v3[o] + EPSF);
      scv[rg] = s;
      shv[rg] = (c3b[o] - m3[o]) * s + b3[o];
    }
    #pragma unroll
    for (int nt = 0; nt < 8; ++nt) {
      int p = nt * 16 + n16;
      if (p < 121) {
        int r = p / 11, c = p - r * 11;
        half4_t vv;
        #pragma unroll
        for (int rg = 0; rg < 4; ++rg)
          vv[rg] = (_Float16)fmaxf(acc[nt][rg] * scv[rg] + shv[rg], 0.f);
        *(half4_t*)(X3 + (r * 16 + c) * 72 + ocb) = vv;
      }
    }
  }
  __syncthreads();

  // ======== conv4 (64->1) + bias + global max -> out[b] ========
  {
    float val = -INFINITY;
    if (t < 81) {
      const int r = t / 9, c = t - (t / 9) * 9;
      float acc = 0.f;
      #pragma unroll
      for (int kr = 0; kr < 3; ++kr)
        #pragma unroll
        for (int kc = 0; kc < 3; ++kc) {
          const _Float16* ip = X3 + ((r + kr) * 16 + (c + kc)) * 72;
          const float* wk = s_w4 + (kr * 3 + kc) * 64;
          #pragma unroll
          for (int cig = 0; cig < 8; ++cig) {
            half8_t x = *(const half8_t*)(ip + cig * 8);
            #pragma unroll
            for (int j = 0; j < 8; ++j)
              acc = fmaf((float)x[j], wk[cig * 8 + j], acc);
          }
        }
      val = acc;
    }
    #pragma unroll
    for (int off = 32; off > 0; off >>= 1)
      val = fmaxf(val, __shfl_down(val, off, 64));
    if (lane == 0) s_red[wave] = val;
    __syncthreads();
    if (t == 0)
      out[b] = fmaxf(fmaxf(s_red[0], s_red[1]), fmaxf(s_red[2], s_red[3])) + c4b[0];
  }
}

// ---------------------------------------------------------------------------
extern "C" void kernel_launch(void* const* d_in, const int* in_sizes, int n_in,
                              void* d_out, int out_size, void* d_ws, size_t ws_size,
                              hipStream_t stream) {
  const float* ts   = (const float*)d_in[0];
  const float* ptm  = (const float*)d_in[1];
  const float* pmt  = (const float*)d_in[2];
  const float* piou = (const float*)d_in[3];
  const int*   mask = (const int*)d_in[4];
  const float* c1w = (const float*)d_in[5];
  const float* c1b = (const float*)d_in[6];
  const float* g1  = (const float*)d_in[7];
  const float* b1  = (const float*)d_in[8];
  const float* m1  = (const float*)d_in[9];
  const float* v1  = (const float*)d_in[10];
  const float* c2w = (const float*)d_in[11];
  const float* c2b = (const float*)d_in[12];
  const float* g2  = (const float*)d_in[13];
  const float* b2  = (const float*)d_in[14];
  const float* m2  = (const float*)d_in[15];
  const float* v2  = (const float*)d_in[16];
  const float* c3w = (const float*)d_in[17];
  const float* c3b = (const float*)d_in[18];
  const float* g3  = (const float*)d_in[19];
  const float* b3  = (const float*)d_in[20];
  const float* m3  = (const float*)d_in[21];
  const float* v3  = (const float*)d_in[22];
  const float* c4w = (const float*)d_in[23];
  const float* c4b = (const float*)d_in[24];

  char* ws = (char*)d_ws;
  _Float16*  w2rep = (_Float16*)(ws + OFF_W2R);
  _Float16*  w3rep = (_Float16*)(ws + OFF_W3R);
  _Float16*  wr1   = (_Float16*)(ws + OFF_WR1);
  float*     wsum1 = (float*)(ws + OFF_WSUM1);

  k_prep<<<314, 256, 0, stream>>>(c1w, c2w, c3w, w2rep, w3rep, wr1, wsum1);
  k_mega<<<NFB, 256, 0, stream>>>(
      ts, ptm, pmt, piou, mask,
      wr1, wsum1, c1b, g1, b1, m1, v1,
      w2rep, c2b, g2, b2, m2, v2,
      w3rep, c3b, g3, b3, m3, v3,
      c4w, c4b, (float*)d_out);
}

// Round 2
// 228.372 us; speedup vs baseline: 1.0785x; 1.0785x over previous
//
#include <hip/hip_runtime.h>
#include <math.h>

#define NFB  512     // B = nf*ns
#define NMEM 30
#define PIX  1024    // 32*32
#define EPSF 1e-5f

typedef _Float16 half8_t __attribute__((ext_vector_type(8)));
typedef _Float16 half4_t __attribute__((ext_vector_type(4)));
typedef float float4_t __attribute__((ext_vector_type(4)));

// workspace layout (byte offsets):
#define OFF_W2R   13631488
#define OFF_W3R   13705216
#define OFF_WR1   13778944
#define OFF_WSUM1 13791232

// ---------------------------------------------------------------------------
// k_prep: all weight repacks in one launch. (unchanged)
// ---------------------------------------------------------------------------
__global__ __launch_bounds__(256) void k_prep(
    const float* __restrict__ c1w, const float* __restrict__ c2w,
    const float* __restrict__ c3w, _Float16* __restrict__ w2rep,
    _Float16* __restrict__ w3rep, _Float16* __restrict__ wr1,
    float* __restrict__ wsum1)
{
  int i = blockIdx.x * 256 + threadIdx.x;
  if (i < 36864) {
    int kr = i / 12288, rem = i - kr * 12288;
    int oc = rem / 192, k = rem - oc * 192;
    int kc = k >> 6, ci = k & 63;
    w2rep[i] = (_Float16)c2w[((oc * 64 + ci) * 3 + kr) * 3 + kc];
  } else if (i < 73728) {
    int j = i - 36864;
    int kr = j / 12288, rem = j - kr * 12288;
    int oc = rem / 192, k = rem - oc * 192;
    int kc = k >> 6, ci = k & 63;
    w3rep[j] = (_Float16)c3w[((oc * 64 + ci) * 3 + kr) * 3 + kc];
  } else if (i < 79872) {
    int j = i - 73728;
    int kr = j / 2048, rem = j - kr * 2048;
    int oc = rem >> 5, k = rem & 31;
    int kc = k >> 3, ci = k & 7;
    _Float16 v = (_Float16)0.f;
    if (kc < 3 && ci < 6)
      v = (_Float16)c1w[((oc * 14 + (2 + ci)) * 3 + kr) * 3 + kc];
    wr1[j] = v;
  } else if (i < 80384) {
    int j = i - 79872;
    int oc = j >> 3, u = j & 7;
    const int uch[8] = {0, 1, 8, 9, 10, 11, 12, 13};
    const float* wp = c1w + (oc * 14 + uch[u]) * 9;
    float s = 0.f;
    #pragma unroll
    for (int k = 0; k < 9; ++k) s += wp[k];
    wsum1[j] = s;
  }
}

// pmt-stats processing chunk: BASE must be a literal so (BASE+j)<15 folds.
#define PROC_CHUNK(CC, BASE, N)                                     \
  _Pragma("unroll")                                                 \
  for (int j = 0; j < (N); ++j) {                                   \
    const int mj = (BASE) + j;                                      \
    float wm = ((mwm >> mj) & 1u) ? 1.f : 0.f;                      \
    float wo = ((mwo >> mj) & 1u) ? 1.f : 0.f;                      \
    float xv[4] = {CC[j].x, CC[j].y, CC[j].z, CC[j].w};             \
    _Pragma("unroll")                                               \
    for (int k = 0; k < 4; ++k) {                                   \
      float x = xv[k];                                              \
      sA[k] = fmaf(wm, x, sA[k]); qA[k] = fmaf(wm * x, x, qA[k]);   \
      sO[k] = fmaf(wo, x, sO[k]); qO[k] = fmaf(wo * x, x, qO[k]);   \
      if (mj < 15) { sG[k] += x; qG[k] = fmaf(x, x, qG[k]); }       \
    }                                                               \
  }

// ---------------------------------------------------------------------------
// k_mega: whole per-b pipeline. 512 blocks x 256 threads, 2 blocks/CU.
// Register budget discipline: every phase peaks < ~110 VGPRs so a 128-VGPR
// allocation never spills (round-1 lesson: spill cost +65 MB HBM writes).
// LDS plan (bytes):
//   IMG [0, 16448)      1028 px * 8 halves
//   X1  [16448, 51008)  240 px * 72 halves
//   X2S [0, 29952)      208 px * 72 halves (conv2 out via registers)
//   X3  [29952, 55296)  176 px * 72 halves
// ---------------------------------------------------------------------------
__global__ __launch_bounds__(256, 2) void k_mega(
    const float* __restrict__ ts, const float* __restrict__ ptm,
    const float* __restrict__ pmt, const float* __restrict__ piou,
    const int* __restrict__ mask,
    const _Float16* __restrict__ wr1, const float* __restrict__ wsum1,
    const float* __restrict__ c1b, const float* __restrict__ g1,
    const float* __restrict__ b1, const float* __restrict__ m1,
    const float* __restrict__ v1,
    const _Float16* __restrict__ w2rep,
    const float* __restrict__ c2b, const float* __restrict__ g2,
    const float* __restrict__ b2, const float* __restrict__ m2,
    const float* __restrict__ v2,
    const _Float16* __restrict__ w3rep,
    const float* __restrict__ c3b, const float* __restrict__ g3,
    const float* __restrict__ b3, const float* __restrict__ m3,
    const float* __restrict__ v3,
    const float* __restrict__ c4w, const float* __restrict__ c4b,
    float* __restrict__ out)
{
  __shared__ __align__(16) char s_buf[55296];
  __shared__ float s_wm[NMEM], s_wo[NMEM], s_pmax[NMEM];
  __shared__ float s_red[4], s_scal[12], s_cnt[4];
  __shared__ unsigned s_mbits[2];
  __shared__ float s_w4[576];   // [k][ci]

  const int b = blockIdx.x, t = threadIdx.x;
  const int lane = t & 63, wave = t >> 6;
  const int n16 = lane & 15, q = lane >> 4;
  _Float16* const IMG = (_Float16*)s_buf;
  _Float16* const X1  = (_Float16*)(s_buf + 16448);
  _Float16* const X2S = (_Float16*)s_buf;
  _Float16* const X3  = (_Float16*)(s_buf + 29952);

  // ======== stage A: stats ========
  // conv4 weights -> LDS (no dependency; hide early)
  for (int i = t; i < 576; i += 256) {
    int ci = i / 9, k = i - ci * 9;
    s_w4[k * 64 + ci] = c4w[i];
  }
  // mask weights + counts + bitmasks (t0)
  if (t == 0) {
    float cum = 0.f, cm = 0.f, cg = 0.f, co = 0.f;
    unsigned bm = 0u, bo = 0u;
    for (int m = 0; m < NMEM; ++m) {
      float f  = (mask[b * NMEM + m] != 0) ? 1.f : 0.f;
      float gg = (cum < 15.f) ? f : 0.f;
      float oo = f - gg;
      cum += f;
      s_wm[m] = f; s_wo[m] = oo;
      if (f > 0.5f)  bm |= (1u << m);
      if (oo > 0.5f) bo |= (1u << m);
      cm += f; cg += gg; co += oo;
    }
    s_cnt[0] = cm; s_cnt[1] = cg; s_cnt[2] = co;
    s_mbits[0] = bm; s_mbits[1] = bo;
  }
  // per-memory spatial max of ptm: 2 passes x 16 float4 in flight (64 VGPR).
  {
    const float* pb = ptm + (size_t)b * NMEM * PIX + lane * 4;
    #pragma unroll
    for (int pass = 0; pass < 2; ++pass) {
      float4 u[4][4];
      #pragma unroll
      for (int k = 0; k < 4; ++k) {
        int m = wave + 4 * (pass * 4 + k);
        if (m < NMEM) {
          #pragma unroll
          for (int j = 0; j < 4; ++j)
            u[k][j] = *(const float4*)(pb + (size_t)m * PIX + j * 256);
        }
      }
      #pragma unroll
      for (int k = 0; k < 4; ++k) {
        int m = wave + 4 * (pass * 4 + k);
        if (m < NMEM) {
          float4 v0 = u[k][0], v1_ = u[k][1], v2_ = u[k][2], v3_ = u[k][3];
          float mx = fmaxf(fmaxf(fmaxf(v0.x, v0.y), fmaxf(v0.z, v0.w)),
                           fmaxf(fmaxf(v1_.x, v1_.y), fmaxf(v1_.z, v1_.w)));
          mx = fmaxf(mx, fmaxf(fmaxf(fmaxf(v2_.x, v2_.y), fmaxf(v2_.z, v2_.w)),
                               fmaxf(fmaxf(v3_.x, v3_.y), fmaxf(v3_.z, v3_.w))));
          #pragma unroll
          for (int off = 32; off > 0; off >>= 1)
            mx = fmaxf(mx, __shfl_down(mx, off, 64));
          if (lane == 0) s_pmax[m] = mx;
        }
      }
    }
  }
  // ts max
  {
    float4 v = ((const float4*)(ts + (size_t)b * PIX))[t];
    float mx = fmaxf(fmaxf(v.x, v.y), fmaxf(v.z, v.w));
    #pragma unroll
    for (int off = 32; off > 0; off >>= 1)
      mx = fmaxf(mx, __shfl_down(mx, off, 64));
    if (lane == 0) s_red[wave] = mx;
  }
  __syncthreads();
  // scalar stats (t0)
  if (t == 0) {
    float maxts = fmaxf(fmaxf(s_red[0], s_red[1]), fmaxf(s_red[2], s_red[3]));
    float sm = 0, sm2 = 0, sg = 0, sg2 = 0, so = 0, so2 = 0;
    for (int m = 0; m < NMEM; ++m) {
      float x = s_pmax[m];
      float gg = s_wm[m] - s_wo[m];
      sm += s_wm[m] * x;  sm2 += s_wm[m] * x * x;
      sg += gg * x;       sg2 += gg * x * x;
      so += s_wo[m] * x;  so2 += s_wo[m] * x * x;
    }
    float cm = s_cnt[0], cg = s_cnt[1], co = s_cnt[2];
    float a = sm / cm, g = sg / cg, o = so / co;
    s_scal[0] = maxts; s_scal[1] = piou[b];
    s_scal[2] = a; s_scal[3] = sqrtf(fmaxf(sm2 / cm - a * a, 0.f));
    s_scal[4] = g; s_scal[5] = sqrtf(fmaxf(sg2 / cg - g * g, 0.f));
    s_scal[6] = o; s_scal[7] = sqrtf(fmaxf(so2 / co - o * o, 0.f));
  }
  // per-pixel pmt stats -> IMG. Pipelined chunks of 6 (peak 12 float4 = 48
  // VGPRs in flight); mask weights via register bitmasks, no LDS in the chain.
  {
    const unsigned mwm = s_mbits[0], mwo = s_mbits[1];
    const float cm = s_cnt[0], co = s_cnt[2];
    const int p0 = t * 4;
    const float* pb = pmt + (size_t)b * NMEM * PIX + p0;
    float sA[4] = {0,0,0,0}, qA[4] = {0,0,0,0};
    float sG[4] = {0,0,0,0}, qG[4] = {0,0,0,0};
    float sO[4] = {0,0,0,0}, qO[4] = {0,0,0,0};
    float4 c0[6], c1[6], c2[6], c3[6], c4[6];
    #pragma unroll
    for (int j = 0; j < 6; ++j) c0[j] = *(const float4*)(pb + (size_t)j * PIX);
    #pragma unroll
    for (int j = 0; j < 6; ++j) c1[j] = *(const float4*)(pb + (size_t)(6 + j) * PIX);
    PROC_CHUNK(c0, 0, 6)
    #pragma unroll
    for (int j = 0; j < 6; ++j) c2[j] = *(const float4*)(pb + (size_t)(12 + j) * PIX);
    PROC_CHUNK(c1, 6, 6)
    #pragma unroll
    for (int j = 0; j < 6; ++j) c3[j] = *(const float4*)(pb + (size_t)(18 + j) * PIX);
    PROC_CHUNK(c2, 12, 6)
    #pragma unroll
    for (int j = 0; j < 6; ++j) c4[j] = *(const float4*)(pb + (size_t)(24 + j) * PIX);
    PROC_CHUNK(c3, 18, 6)
    PROC_CHUNK(c4, 24, 6)
    half8_t* ob = (half8_t*)(IMG) + p0;
    #pragma unroll
    for (int j = 0; j < 4; ++j) {
      float m0 = sA[j] / cm;   float d0 = sqrtf(fmaxf(qA[j] / cm - m0 * m0, 0.f));
      float m1_ = sG[j] / 15.f; float d1 = sqrtf(fmaxf(qG[j] / 15.f - m1_ * m1_, 0.f));
      float m2_ = sO[j] / co;   float d2 = sqrtf(fmaxf(qO[j] / co - m2_ * m2_, 0.f));
      half8_t v;
      v[0] = (_Float16)m0;  v[1] = (_Float16)d0;
      v[2] = (_Float16)m1_; v[3] = (_Float16)d1;
      v[4] = (_Float16)m2_; v[5] = (_Float16)d2;
      v[6] = (_Float16)0.f; v[7] = (_Float16)0.f;
      ob[j] = v;
    }
    if (t < 4) {   // zero the 4 pad pixels (1024..1027)
      half8_t z = {(_Float16)0.f,(_Float16)0.f,(_Float16)0.f,(_Float16)0.f,
                   (_Float16)0.f,(_Float16)0.f,(_Float16)0.f,(_Float16)0.f};
      ((half8_t*)IMG)[1024 + t] = z;
    }
  }
  __syncthreads();

  // ======== conv1 (MFMA) + BN + ReLU + 2x2 maxpool -> X1 (LDS, stride 72) ====
  {
    const int ocA = wave * 16 + n16;
    half8_t af[3];
    #pragma unroll
    for (int kr = 0; kr < 3; ++kr)
      af[kr] = *(const half8_t*)(wr1 + (kr * 64 + ocA) * 32 + q * 8);
    const int oc0 = wave * 16 + q * 4;
    float scv[4], shv[4], cst[4];
    #pragma unroll
    for (int rg = 0; rg < 4; ++rg) {
      int oc = oc0 + rg;
      float s = g1[oc] * rsqrtf(v1[oc] + EPSF);
      scv[rg] = s;
      shv[rg] = (c1b[oc] - m1[oc]) * s + b1[oc];
      float c = 0.f;
      #pragma unroll
      for (int u = 0; u < 8; ++u) c = fmaf(wsum1[oc * 8 + u], s_scal[u], c);
      cst[rg] = c;
    }
    #pragma unroll 1
    for (int pr = 0; pr < 15; ++pr) {
      const int r0 = pr * 2;
      float4_t acc[2][2];
      #pragma unroll
      for (int row = 0; row < 2; ++row)
        #pragma unroll
        for (int tt = 0; tt < 2; ++tt)
          acc[row][tt] = (float4_t){0.f, 0.f, 0.f, 0.f};
      #pragma unroll
      for (int row = 0; row < 2; ++row) {
        #pragma unroll
        for (int kr = 0; kr < 3; ++kr) {
          const int ip = (r0 + row + kr) * 32 + n16 + q;
          #pragma unroll
          for (int tt = 0; tt < 2; ++tt) {
            half8_t bf = *(const half8_t*)(IMG + (ip + tt * 16) * 8);
            acc[row][tt] = __builtin_amdgcn_mfma_f32_16x16x32_f16(
                af[kr], bf, acc[row][tt], 0, 0, 0);
          }
        }
      }
      #pragma unroll
      for (int tt = 0; tt < 2; ++tt) {
        float mm[4];
        #pragma unroll
        for (int j = 0; j < 4; ++j) {
          float m = fmaxf(acc[0][tt][j], acc[1][tt][j]);
          mm[j] = fmaxf(m, __shfl_xor(m, 1, 64));
        }
        if ((n16 & 1) == 0) {
          int pc = tt * 8 + (n16 >> 1);
          half4_t vv;
          if (pc < 15) {
            #pragma unroll
            for (int rg = 0; rg < 4; ++rg)
              vv[rg] = (_Float16)fmaxf(scv[rg] * (mm[rg] + cst[rg]) + shv[rg], 0.f);
          } else {
            vv[0] = (_Float16)0.f; vv[1] = (_Float16)0.f;
            vv[2] = (_Float16)0.f; vv[3] = (_Float16)0.f;
          }
          *(half4_t*)(X1 + (pr * 16 + pc) * 72 + oc0) = vv;
        }
      }
    }
  }
  __syncthreads();

  // ======== conv2 (MFMA): X1(LDS) -> registers -> X2S(LDS) ========
  // weights double-buffered (peak 2x6 half8 = 48 VGPR, not 3x6 = 72)
  {
    int base72[11];
    #pragma unroll
    for (int nt = 0; nt < 11; ++nt) {
      int p = nt * 16 + n16;
      int pe = (p < 169) ? p : 168;
      int r = pe / 13, c = pe - r * 13;
      base72[nt] = (r * 16 + c) * 72;
    }
    float4_t acc[11];
    #pragma unroll
    for (int nt = 0; nt < 11; ++nt) acc[nt] = (float4_t){0.f, 0.f, 0.f, 0.f};
    const int ocA = wave * 16 + n16;

    auto mfma_kr = [&](const half8_t (&af)[6], int kr) {
      const int krbase = kr * (16 * 72);
      #pragma unroll
      for (int ks = 0; ks < 6; ++ks) {
        const int k0 = ks * 32 + q * 8;
        const int kadd = krbase + (k0 >> 6) * 72 + (k0 & 63);
        #pragma unroll
        for (int nt = 0; nt < 11; ++nt) {
          half8_t bf = *(const half8_t*)(X1 + base72[nt] + kadd);
          acc[nt] = __builtin_amdgcn_mfma_f32_16x16x32_f16(af[ks], bf, acc[nt], 0, 0, 0);
        }
      }
    };

    half8_t afA[6], afB[6];
    {
      const half8_t* wp = (const half8_t*)(w2rep + (size_t)(0 * 64 + ocA) * 192 + q * 8);
      #pragma unroll
      for (int ks = 0; ks < 6; ++ks) afA[ks] = wp[ks * 4];
    }
    {
      const half8_t* wp = (const half8_t*)(w2rep + (size_t)(1 * 64 + ocA) * 192 + q * 8);
      #pragma unroll
      for (int ks = 0; ks < 6; ++ks) afB[ks] = wp[ks * 4];
      mfma_kr(afA, 0);
    }
    {
      const half8_t* wp = (const half8_t*)(w2rep + (size_t)(2 * 64 + ocA) * 192 + q * 8);
      #pragma unroll
      for (int ks = 0; ks < 6; ++ks) afA[ks] = wp[ks * 4];
      mfma_kr(afB, 1);
    }
    mfma_kr(afA, 2);

    const int ocb = wave * 16 + q * 4;
    float scv[4], shv[4];
    #pragma unroll
    for (int rg = 0; rg < 4; ++rg) {
      int o = ocb + rg;
      float s = g2[o] * rsqrtf(v2[o] + EPSF);
      scv[rg] = s;
      shv[rg] = (c2b[o] - m2[o]) * s + b2[o];
    }
    half4_t vout[11];
    #pragma unroll
    for (int nt = 0; nt < 11; ++nt) {
      #pragma unroll
      for (int rg = 0; rg < 4; ++rg)
        vout[nt][rg] = (_Float16)fmaxf(acc[nt][rg] * scv[rg] + shv[rg], 0.f);
    }
    __syncthreads();   // all waves done reading X1/IMG; X2S region now free
    #pragma unroll
    for (int nt = 0; nt < 11; ++nt) {
      int p = nt * 16 + n16;
      if (p < 169) {
        int r = p / 13, c = p - r * 13;
        *(half4_t*)(X2S + (r * 16 + c) * 72 + ocb) = vout[nt];
      }
    }
  }
  __syncthreads();

  // ======== conv3 (MFMA): X2S -> X3 (LDS) ========
  {
    int base72[8];
    #pragma unroll
    for (int nt = 0; nt < 8; ++nt) {
      int p = nt * 16 + n16;
      int pe = (p < 121) ? p : 120;
      int r = pe / 11, c = pe - r * 11;
      base72[nt] = (r * 16 + c) * 72;
    }
    float4_t acc[8];
    #pragma unroll
    for (int nt = 0; nt < 8; ++nt) acc[nt] = (float4_t){0.f, 0.f, 0.f, 0.f};
    const int ocA = wave * 16 + n16;

    auto mfma_kr3 = [&](const half8_t (&af)[6], int kr) {
      const int krbase = kr * (16 * 72);
      #pragma unroll
      for (int ks = 0; ks < 6; ++ks) {
        const int k0 = ks * 32 + q * 8;
        const int kadd = krbase + (k0 >> 6) * 72 + (k0 & 63);
        #pragma unroll
        for (int nt = 0; nt < 8; ++nt) {
          half8_t bf = *(const half8_t*)(X2S + base72[nt] + kadd);
          acc[nt] = __builtin_amdgcn_mfma_f32_16x16x32_f16(af[ks], bf, acc[nt], 0, 0, 0);
        }
      }
    };

    half8_t afA[6], afB[6];
    {
      const half8_t* wp = (const half8_t*)(w3rep + (size_t)(0 * 64 + ocA) * 192 + q * 8);
      #pragma unroll
      for (int ks = 0; ks < 6; ++ks) afA[ks] = wp[ks * 4];
    }
    {
      const half8_t* wp = (const half8_t*)(w3rep + (size_t)(1 * 64 + ocA) * 192 + q * 8);
      #pragma unroll
      for (int ks = 0; ks < 6; ++ks) afB[ks] = wp[ks * 4];
      mfma_kr3(afA, 0);
    }
    {
      const half8_t* wp = (const half8_t*)(w3rep + (size_t)(2 * 64 + ocA) * 192 + q * 8);
      #pragma unroll
      for (int ks = 0; ks < 6; ++ks) afA[ks] = wp[ks * 4];
      mfma_kr3(afB, 1);
    }
    mfma_kr3(afA, 2);

    const int ocb = wave * 16 + q * 4;
    float scv[4], shv[4];
    #pragma unroll
    for (int rg = 0; rg < 4; ++rg) {
      int o = ocb + rg;
      float s = g3[o] * rsqrtf(v3[o] + EPSF);
      scv[rg] = s;
      shv[rg] = (c3b[o] - m3[o]) * s + b3[o];
    }
    #pragma unroll
    for (int nt = 0; nt < 8; ++nt) {
      int p = nt * 16 + n16;
      if (p < 121) {
        int r = p / 11, c = p - r * 11;
        half4_t vv;
        #pragma unroll
        for (int rg = 0; rg < 4; ++rg)
          vv[rg] = (_Float16)fmaxf(acc[nt][rg] * scv[rg] + shv[rg], 0.f);
        *(half4_t*)(X3 + (r * 16 + c) * 72 + ocb) = vv;
      }
    }
  }
  __syncthreads();

  // ======== conv4 (64->1) + bias + global max -> out[b] ========
  {
    float val = -INFINITY;
    if (t < 81) {
      const int r = t / 9, c = t - (t / 9) * 9;
      float acc = 0.f;
      #pragma unroll
      for (int kr = 0; kr < 3; ++kr)
        #pragma unroll
        for (int kc = 0; kc < 3; ++kc) {
          const _Float16* ip = X3 + ((r + kr) * 16 + (c + kc)) * 72;
          const float* wk = s_w4 + (kr * 3 + kc) * 64;
          #pragma unroll
          for (int cig = 0; cig < 8; ++cig) {
            half8_t x = *(const half8_t*)(ip + cig * 8);
            #pragma unroll
            for (int j = 0; j < 8; ++j)
              acc = fmaf((float)x[j], wk[cig * 8 + j], acc);
          }
        }
      val = acc;
    }
    #pragma unroll
    for (int off = 32; off > 0; off >>= 1)
      val = fmaxf(val, __shfl_down(val, off, 64));
    if (lane == 0) s_red[wave] = val;
    __syncthreads();
    if (t == 0)
      out[b] = fmaxf(fmaxf(s_red[0], s_red[1]), fmaxf(s_red[2], s_red[3])) + c4b[0];
  }
}

// ---------------------------------------------------------------------------
extern "C" void kernel_launch(void* const* d_in, const int* in_sizes, int n_in,
                              void* d_out, int out_size, void* d_ws, size_t ws_size,
                              hipStream_t stream) {
  const float* ts   = (const float*)d_in[0];
  const float* ptm  = (const float*)d_in[1];
  const float* pmt  = (const float*)d_in[2];
  const float* piou = (const float*)d_in[3];
  const int*   mask = (const int*)d_in[4];
  const float* c1w = (const float*)d_in[5];
  const float* c1b = (const float*)d_in[6];
  const float* g1  = (const float*)d_in[7];
  const float* b1  = (const float*)d_in[8];
  const float* m1  = (const float*)d_in[9];
  const float* v1  = (const float*)d_in[10];
  const float* c2w = (const float*)d_in[11];
  const float* c2b = (const float*)d_in[12];
  const float* g2  = (const float*)d_in[13];
  const float* b2  = (const float*)d_in[14];
  const float* m2  = (const float*)d_in[15];
  const float* v2  = (const float*)d_in[16];
  const float* c3w = (const float*)d_in[17];
  const float* c3b = (const float*)d_in[18];
  const float* g3  = (const float*)d_in[19];
  const float* b3  = (const float*)d_in[20];
  const float* m3  = (const float*)d_in[21];
  const float* v3  = (const float*)d_in[22];
  const float* c4w = (const float*)d_in[23];
  const float* c4b = (const float*)d_in[24];

  char* ws = (char*)d_ws;
  _Float16*  w2rep = (_Float16*)(ws + OFF_W2R);
  _Float16*  w3rep = (_Float16*)(ws + OFF_W3R);
  _Float16*  wr1   = (_Float16*)(ws + OFF_WR1);
  float*     wsum1 = (float*)(ws + OFF_WSUM1);

  k_prep<<<314, 256, 0, stream>>>(c1w, c2w, c3w, w2rep, w3rep, wr1, wsum1);
  k_mega<<<NFB, 256, 0, stream>>>(
      ts, ptm, pmt, piou, mask,
      wr1, wsum1, c1b, g1, b1, m1, v1,
      w2rep, c2b, g2, b2, m2, v2,
      w3rep, c3b, g3, b3, m3, v3,
      c4w, c4b, (float*)d_out);
}

// Round 9
// 221.327 us; speedup vs baseline: 1.1129x; 1.0318x over previous
//
#include <hip/hip_runtime.h>
#include <math.h>

#define NFB  512     // B = nf*ns
#define NMEM 30
#define PIX  1024    // 32*32
#define EPSF 1e-5f

typedef _Float16 half8_t __attribute__((ext_vector_type(8)));
typedef _Float16 half4_t __attribute__((ext_vector_type(4)));
typedef float float4_t __attribute__((ext_vector_type(4)));

// workspace layout (byte offsets):
// img_ws  (f16) [512][1024][8] @ 0          size 8,388,608
// scal_ws (f32) [512][8]       @ 8,388,608  size 16,384
// w2rep   (f16) [3][64][192]   @ 13,631,488 size 73,728
// w3rep   (f16) [3][64][192]   @ 13,705,216 size 73,728
// wr1     (f16) [3][64][32]    @ 13,778,944 size 12,288
// wsum1   (f32) [64][8]        @ 13,791,232 size 2,048
#define OFF_SCAL  8388608
#define OFF_W2R   13631488
#define OFF_W3R   13705216
#define OFF_WR1   13778944
#define OFF_WSUM1 13791232

// pmt-stats chunk (2 px/thread, 10 memories). BASE literal so (mj<15) folds.
#define PROC2(CC, BASE)                                              \
  _Pragma("unroll")                                                  \
  for (int j = 0; j < 10; ++j) {                                     \
    const int mj = (BASE) + j;                                       \
    float wm = ((mwm >> mj) & 1u) ? 1.f : 0.f;                       \
    float wo = ((mwo >> mj) & 1u) ? 1.f : 0.f;                       \
    float xv[2] = {CC[j].x, CC[j].y};                                \
    _Pragma("unroll")                                                \
    for (int k = 0; k < 2; ++k) {                                    \
      float x = xv[k];                                               \
      sA[k] = fmaf(wm, x, sA[k]); qA[k] = fmaf(wm * x, x, qA[k]);    \
      sO[k] = fmaf(wo, x, sO[k]); qO[k] = fmaf(wo * x, x, qO[k]);    \
      if (mj < 15) { sG[k] += x; qG[k] = fmaf(x, x, qG[k]); }        \
    }                                                                \
  }

// ---------------------------------------------------------------------------
// k_stats: 1850 blocks x 256 threads, three roles by blockIdx:
//   [0,314)      weight repack (old k_prep)
//   [314,826)    per-b ptm spatial max + ts max + 8 scalar stats -> scal_ws
//   [826,1850)   per-(b,half) pmt per-pixel stats -> img_ws (no LDS/barriers)
// ---------------------------------------------------------------------------
__global__ __launch_bounds__(256) void k_stats(
    const float* __restrict__ ts, const float* __restrict__ ptm,
    const float* __restrict__ pmt, const float* __restrict__ piou,
    const int* __restrict__ mask,
    const float* __restrict__ c1w, const float* __restrict__ c2w,
    const float* __restrict__ c3w,
    _Float16* __restrict__ w2rep, _Float16* __restrict__ w3rep,
    _Float16* __restrict__ wr1, float* __restrict__ wsum1,
    _Float16* __restrict__ img, float* __restrict__ scal)
{
  __shared__ float s_pmax[NMEM];
  __shared__ float s_red[4];
  const int bid = blockIdx.x, t = threadIdx.x;

  if (bid < 314) {
    // ---- role P: weight repack ----
    int i = bid * 256 + t;
    if (i < 36864) {
      int kr = i / 12288, rem = i - kr * 12288;
      int oc = rem / 192, k = rem - oc * 192;
      int kc = k >> 6, ci = k & 63;
      w2rep[i] = (_Float16)c2w[((oc * 64 + ci) * 3 + kr) * 3 + kc];
    } else if (i < 73728) {
      int j = i - 36864;
      int kr = j / 12288, rem = j - kr * 12288;
      int oc = rem / 192, k = rem - oc * 192;
      int kc = k >> 6, ci = k & 63;
      w3rep[j] = (_Float16)c3w[((oc * 64 + ci) * 3 + kr) * 3 + kc];
    } else if (i < 79872) {
      int j = i - 73728;
      int kr = j / 2048, rem = j - kr * 2048;
      int oc = rem >> 5, k = rem & 31;
      int kc = k >> 3, ci = k & 7;
      _Float16 v = (_Float16)0.f;
      if (kc < 3 && ci < 6)
        v = (_Float16)c1w[((oc * 14 + (2 + ci)) * 3 + kr) * 3 + kc];
      wr1[j] = v;
    } else if (i < 80384) {
      int j = i - 79872;
      int oc = j >> 3, u = j & 7;
      const int uch[8] = {0, 1, 8, 9, 10, 11, 12, 13};
      const float* wp = c1w + (oc * 14 + uch[u]) * 9;
      float s = 0.f;
      #pragma unroll
      for (int k = 0; k < 9; ++k) s += wp[k];
      wsum1[j] = s;
    }
    return;
  }

  if (bid < 826) {
    // ---- role A: ptm max + ts max + scalar stats for b ----
    const int b = bid - 314;
    const int lane = t & 63, wave = t >> 6;
    {
      const float* pb = ptm + (size_t)b * NMEM * PIX + lane * 4;
      #pragma unroll
      for (int pass = 0; pass < 2; ++pass) {
        float4 u[4][4];
        #pragma unroll
        for (int k = 0; k < 4; ++k) {
          int m = wave + 4 * (pass * 4 + k);
          if (m < NMEM) {
            #pragma unroll
            for (int j = 0; j < 4; ++j)
              u[k][j] = *(const float4*)(pb + (size_t)m * PIX + j * 256);
          }
        }
        #pragma unroll
        for (int k = 0; k < 4; ++k) {
          int m = wave + 4 * (pass * 4 + k);
          if (m < NMEM) {
            float4 v0 = u[k][0], v1_ = u[k][1], v2_ = u[k][2], v3_ = u[k][3];
            float mx = fmaxf(fmaxf(fmaxf(v0.x, v0.y), fmaxf(v0.z, v0.w)),
                             fmaxf(fmaxf(v1_.x, v1_.y), fmaxf(v1_.z, v1_.w)));
            mx = fmaxf(mx, fmaxf(fmaxf(fmaxf(v2_.x, v2_.y), fmaxf(v2_.z, v2_.w)),
                                 fmaxf(fmaxf(v3_.x, v3_.y), fmaxf(v3_.z, v3_.w))));
            #pragma unroll
            for (int off = 32; off > 0; off >>= 1)
              mx = fmaxf(mx, __shfl_down(mx, off, 64));
            if (lane == 0) s_pmax[m] = mx;
          }
        }
      }
    }
    {
      float4 v = ((const float4*)(ts + (size_t)b * PIX))[t];
      float mx = fmaxf(fmaxf(v.x, v.y), fmaxf(v.z, v.w));
      #pragma unroll
      for (int off = 32; off > 0; off >>= 1)
        mx = fmaxf(mx, __shfl_down(mx, off, 64));
      if (lane == 0) s_red[wave] = mx;
    }
    __syncthreads();
    if (t == 0) {
      float maxts = fmaxf(fmaxf(s_red[0], s_red[1]), fmaxf(s_red[2], s_red[3]));
      float cum = 0.f, cm = 0.f, cg = 0.f, co = 0.f;
      float sm = 0, sm2 = 0, sg = 0, sg2 = 0, so = 0, so2 = 0;
      for (int m = 0; m < NMEM; ++m) {
        float f  = (mask[b * NMEM + m] != 0) ? 1.f : 0.f;
        float gg = (cum < 15.f) ? f : 0.f;
        float oo = f - gg;
        cum += f;
        float x = s_pmax[m];
        sm += f * x;  sm2 += f * x * x;
        sg += gg * x; sg2 += gg * x * x;
        so += oo * x; so2 += oo * x * x;
        cm += f; cg += gg; co += oo;
      }
      float a = sm / cm, g = sg / cg, o = so / co;
      float* sc = scal + b * 8;
      sc[0] = maxts; sc[1] = piou[b];
      sc[2] = a; sc[3] = sqrtf(fmaxf(sm2 / cm - a * a, 0.f));
      sc[4] = g; sc[5] = sqrtf(fmaxf(sg2 / cg - g * g, 0.f));
      sc[6] = o; sc[7] = sqrtf(fmaxf(so2 / co - o * o, 0.f));
    }
    return;
  }

  // ---- role B: pmt per-pixel stats (2 px/thread, 2 blocks per b) ----
  {
    const int j0 = bid - 826;            // 0..1023
    const int b = j0 >> 1;
    const int px0 = (j0 & 1) * 512 + t * 2;
    const float* pb = pmt + (size_t)b * NMEM * PIX + px0;
    float2 ca[10], cb[10];
    #pragma unroll
    for (int j = 0; j < 10; ++j) ca[j] = *(const float2*)(pb + (size_t)j * PIX);
    #pragma unroll
    for (int j = 0; j < 10; ++j) cb[j] = *(const float2*)(pb + (size_t)(10 + j) * PIX);
    // mask weights (uniform across lanes -> scalar loads/ALU, overlaps latency)
    unsigned mwm = 0u, mwo = 0u;
    float cum = 0.f, cm = 0.f, co = 0.f;
    for (int m = 0; m < NMEM; ++m) {
      int f = (mask[b * NMEM + m] != 0) ? 1 : 0;
      int oo = (f && (cum >= 15.f)) ? 1 : 0;
      cum += (float)f;
      if (f)  mwm |= (1u << m);
      if (oo) mwo |= (1u << m);
      cm += (float)f; co += (float)oo;
    }
    float sA[2] = {0,0}, qA[2] = {0,0};
    float sG[2] = {0,0}, qG[2] = {0,0};
    float sO[2] = {0,0}, qO[2] = {0,0};
    PROC2(ca, 0)
    #pragma unroll
    for (int j = 0; j < 10; ++j) ca[j] = *(const float2*)(pb + (size_t)(20 + j) * PIX);
    PROC2(cb, 10)
    PROC2(ca, 20)
    half8_t* ob = (half8_t*)img + (size_t)b * 1024 + px0;
    #pragma unroll
    for (int k = 0; k < 2; ++k) {
      float m0 = sA[k] / cm;    float d0 = sqrtf(fmaxf(qA[k] / cm - m0 * m0, 0.f));
      float m1_ = sG[k] / 15.f; float d1 = sqrtf(fmaxf(qG[k] / 15.f - m1_ * m1_, 0.f));
      float m2_ = sO[k] / co;   float d2 = sqrtf(fmaxf(qO[k] / co - m2_ * m2_, 0.f));
      half8_t v;
      v[0] = (_Float16)m0;  v[1] = (_Float16)d0;
      v[2] = (_Float16)m1_; v[3] = (_Float16)d1;
      v[4] = (_Float16)m2_; v[5] = (_Float16)d2;
      v[6] = (_Float16)0.f; v[7] = (_Float16)0.f;
      ob[k] = v;
    }
  }
}

// ---------------------------------------------------------------------------
// k_conv: conv pipeline only. 512 blocks x 256 threads.
// LDS plan (bytes), trimmed to exact extents for 3-blocks/CU capacity:
//   IMG [0, 16432)       1027 px * 16 B
//   X1  [16432, 50848)   239 px * 144 B
//   X2S [0, 29520)       205 px * 144 B   (IMG+X1 dead by then)
//   X3  [29520, 54144)   171 px * 144 B
//   w4s [0, 2304)        576 f32          (X2S dead; staged post-conv3)
// ---------------------------------------------------------------------------
__global__ __launch_bounds__(256, 2) void k_conv(
    const _Float16* __restrict__ img, const float* __restrict__ scal,
    const _Float16* __restrict__ wr1, const float* __restrict__ wsum1,
    const float* __restrict__ c1b, const float* __restrict__ g1,
    const float* __restrict__ b1, const float* __restrict__ m1,
    const float* __restrict__ v1,
    const _Float16* __restrict__ w2rep,
    const float* __restrict__ c2b, const float* __restrict__ g2,
    const float* __restrict__ b2, const float* __restrict__ m2,
    const float* __restrict__ v2,
    const _Float16* __restrict__ w3rep,
    const float* __restrict__ c3b, const float* __restrict__ g3,
    const float* __restrict__ b3, const float* __restrict__ m3,
    const float* __restrict__ v3,
    const float* __restrict__ c4w, const float* __restrict__ c4b,
    float* __restrict__ out)
{
  __shared__ __align__(16) char s_buf[54144];
  __shared__ float s_red[4], s_scal[8];

  const int b = blockIdx.x, t = threadIdx.x;
  const int lane = t & 63, wave = t >> 6;
  const int n16 = lane & 15, q = lane >> 4;
  _Float16* const IMG = (_Float16*)s_buf;
  _Float16* const X1  = (_Float16*)(s_buf + 16432);
  _Float16* const X2S = (_Float16*)s_buf;
  _Float16* const X3  = (_Float16*)(s_buf + 29520);

  // ======== stage in: IMG from workspace + scalars ========
  {
    const half8_t* src = (const half8_t*)img + (size_t)b * 1024;
    half8_t* dst = (half8_t*)IMG;
    for (int i = t; i < 1027; i += 256) {
      half8_t v = {(_Float16)0.f,(_Float16)0.f,(_Float16)0.f,(_Float16)0.f,
                   (_Float16)0.f,(_Float16)0.f,(_Float16)0.f,(_Float16)0.f};
      if (i < 1024) v = src[i];
      dst[i] = v;
    }
    if (t < 8) s_scal[t] = scal[b * 8 + t];
  }
  __syncthreads();

  // ======== conv1 (MFMA) + BN + ReLU + 2x2 maxpool -> X1 (stride 72) ========
  {
    const int ocA = wave * 16 + n16;
    half8_t af[3];
    #pragma unroll
    for (int kr = 0; kr < 3; ++kr)
      af[kr] = *(const half8_t*)(wr1 + (kr * 64 + ocA) * 32 + q * 8);
    const int oc0 = wave * 16 + q * 4;
    float scv[4], shv[4], cst[4];
    #pragma unroll
    for (int rg = 0; rg < 4; ++rg) {
      int oc = oc0 + rg;
      float s = g1[oc] * rsqrtf(v1[oc] + EPSF);
      scv[rg] = s;
      shv[rg] = (c1b[oc] - m1[oc]) * s + b1[oc];
      float c = 0.f;
      #pragma unroll
      for (int u = 0; u < 8; ++u) c = fmaf(wsum1[oc * 8 + u], s_scal[u], c);
      cst[rg] = c;
    }
    #pragma unroll 1
    for (int pr = 0; pr < 15; ++pr) {
      const int r0 = pr * 2;
      float4_t acc[2][2];
      #pragma unroll
      for (int row = 0; row < 2; ++row)
        #pragma unroll
        for (int tt = 0; tt < 2; ++tt)
          acc[row][tt] = (float4_t){0.f, 0.f, 0.f, 0.f};
      #pragma unroll
      for (int row = 0; row < 2; ++row) {
        #pragma unroll
        for (int kr = 0; kr < 3; ++kr) {
          const int ip = (r0 + row + kr) * 32 + n16 + q;
          #pragma unroll
          for (int tt = 0; tt < 2; ++tt) {
            half8_t bf = *(const half8_t*)(IMG + (ip + tt * 16) * 8);
            acc[row][tt] = __builtin_amdgcn_mfma_f32_16x16x32_f16(
                af[kr], bf, acc[row][tt], 0, 0, 0);
          }
        }
      }
      #pragma unroll
      for (int tt = 0; tt < 2; ++tt) {
        float mm[4];
        #pragma unroll
        for (int j = 0; j < 4; ++j) {
          float m = fmaxf(acc[0][tt][j], acc[1][tt][j]);
          mm[j] = fmaxf(m, __shfl_xor(m, 1, 64));
        }
        int pc = tt * 8 + (n16 >> 1);
        if (((n16 & 1) == 0) && pc < 15) {
          half4_t vv;
          #pragma unroll
          for (int rg = 0; rg < 4; ++rg)
            vv[rg] = (_Float16)fmaxf(scv[rg] * (mm[rg] + cst[rg]) + shv[rg], 0.f);
          *(half4_t*)(X1 + (pr * 16 + pc) * 72 + oc0) = vv;
        }
      }
    }
  }
  __syncthreads();

  // ======== conv2 (MFMA): X1 -> registers -> X2S ========
  {
    int base72[11];
    #pragma unroll
    for (int nt = 0; nt < 11; ++nt) {
      int p = nt * 16 + n16;
      int pe = (p < 169) ? p : 168;
      int r = pe / 13, c = pe - r * 13;
      base72[nt] = (r * 16 + c) * 72;
    }
    float4_t acc[11];
    #pragma unroll
    for (int nt = 0; nt < 11; ++nt) acc[nt] = (float4_t){0.f, 0.f, 0.f, 0.f};
    const int ocA = wave * 16 + n16;

    auto mfma_kr = [&](const half8_t (&af)[6], int kr) {
      const int krbase = kr * (16 * 72);
      #pragma unroll
      for (int ks = 0; ks < 6; ++ks) {
        const int k0 = ks * 32 + q * 8;
        const int kadd = krbase + (k0 >> 6) * 72 + (k0 & 63);
        #pragma unroll
        for (int nt = 0; nt < 11; ++nt) {
          half8_t bf = *(const half8_t*)(X1 + base72[nt] + kadd);
          acc[nt] = __builtin_amdgcn_mfma_f32_16x16x32_f16(af[ks], bf, acc[nt], 0, 0, 0);
        }
      }
    };

    half8_t afA[6], afB[6];
    {
      const half8_t* wp = (const half8_t*)(w2rep + (size_t)(0 * 64 + ocA) * 192 + q * 8);
      #pragma unroll
      for (int ks = 0; ks < 6; ++ks) afA[ks] = wp[ks * 4];
    }
    {
      const half8_t* wp = (const half8_t*)(w2rep + (size_t)(1 * 64 + ocA) * 192 + q * 8);
      #pragma unroll
      for (int ks = 0; ks < 6; ++ks) afB[ks] = wp[ks * 4];
      mfma_kr(afA, 0);
    }
    {
      const half8_t* wp = (const half8_t*)(w2rep + (size_t)(2 * 64 + ocA) * 192 + q * 8);
      #pragma unroll
      for (int ks = 0; ks < 6; ++ks) afA[ks] = wp[ks * 4];
      mfma_kr(afB, 1);
    }
    mfma_kr(afA, 2);

    const int ocb = wave * 16 + q * 4;
    float scv[4], shv[4];
    #pragma unroll
    for (int rg = 0; rg < 4; ++rg) {
      int o = ocb + rg;
      float s = g2[o] * rsqrtf(v2[o] + EPSF);
      scv[rg] = s;
      shv[rg] = (c2b[o] - m2[o]) * s + b2[o];
    }
    half4_t vout[11];
    #pragma unroll
    for (int nt = 0; nt < 11; ++nt) {
      #pragma unroll
      for (int rg = 0; rg < 4; ++rg)
        vout[nt][rg] = (_Float16)fmaxf(acc[nt][rg] * scv[rg] + shv[rg], 0.f);
    }
    __syncthreads();   // all waves done reading X1/IMG; X2S region now free
    #pragma unroll
    for (int nt = 0; nt < 11; ++nt) {
      int p = nt * 16 + n16;
      if (p < 169) {
        int r = p / 13, c = p - r * 13;
        *(half4_t*)(X2S + (r * 16 + c) * 72 + ocb) = vout[nt];
      }
    }
  }
  __syncthreads();

  // conv4 weight prefetch to registers (issues early, lands during conv3)
  float w4r0 = c4w[t];
  float w4r1 = c4w[256 + t];
  float w4r2 = (t < 64) ? c4w[512 + t] : 0.f;

  // ======== conv3 (MFMA): X2S -> X3 ========
  {
    int base72[8];
    #pragma unroll
    for (int nt = 0; nt < 8; ++nt) {
      int p = nt * 16 + n16;
      int pe = (p < 121) ? p : 120;
      int r = pe / 11, c = pe - r * 11;
      base72[nt] = (r * 16 + c) * 72;
    }
    float4_t acc[8];
    #pragma unroll
    for (int nt = 0; nt < 8; ++nt) acc[nt] = (float4_t){0.f, 0.f, 0.f, 0.f};
    const int ocA = wave * 16 + n16;

    auto mfma_kr3 = [&](const half8_t (&af)[6], int kr) {
      const int krbase = kr * (16 * 72);
      #pragma unroll
      for (int ks = 0; ks < 6; ++ks) {
        const int k0 = ks * 32 + q * 8;
        const int kadd = krbase + (k0 >> 6) * 72 + (k0 & 63);
        #pragma unroll
        for (int nt = 0; nt < 8; ++nt) {
          half8_t bf = *(const half8_t*)(X2S + base72[nt] + kadd);
          acc[nt] = __builtin_amdgcn_mfma_f32_16x16x32_f16(af[ks], bf, acc[nt], 0, 0, 0);
        }
      }
    };

    half8_t afA[6], afB[6];
    {
      const half8_t* wp = (const half8_t*)(w3rep + (size_t)(0 * 64 + ocA) * 192 + q * 8);
      #pragma unroll
      for (int ks = 0; ks < 6; ++ks) afA[ks] = wp[ks * 4];
    }
    {
      const half8_t* wp = (const half8_t*)(w3rep + (size_t)(1 * 64 + ocA) * 192 + q * 8);
      #pragma unroll
      for (int ks = 0; ks < 6; ++ks) afB[ks] = wp[ks * 4];
      mfma_kr3(afA, 0);
    }
    {
      const half8_t* wp = (const half8_t*)(w3rep + (size_t)(2 * 64 + ocA) * 192 + q * 8);
      #pragma unroll
      for (int ks = 0; ks < 6; ++ks) afA[ks] = wp[ks * 4];
      mfma_kr3(afB, 1);
    }
    mfma_kr3(afA, 2);

    const int ocb = wave * 16 + q * 4;
    float scv[4], shv[4];
    #pragma unroll
    for (int rg = 0; rg < 4; ++rg) {
      int o = ocb + rg;
      float s = g3[o] * rsqrtf(v3[o] + EPSF);
      scv[rg] = s;
      shv[rg] = (c3b[o] - m3[o]) * s + b3[o];
    }
    #pragma unroll
    for (int nt = 0; nt < 8; ++nt) {
      int p = nt * 16 + n16;
      if (p < 121) {
        int r = p / 11, c = p - r * 11;
        half4_t vv;
        #pragma unroll
        for (int rg = 0; rg < 4; ++rg)
          vv[rg] = (_Float16)fmaxf(acc[nt][rg] * scv[rg] + shv[rg], 0.f);
        *(half4_t*)(X3 + (r * 16 + c) * 72 + ocb) = vv;
      }
    }
  }
  __syncthreads();

  // stage conv4 weights into dead X2S region: w4s[k*64+ci]
  {
    float* w4s = (float*)s_buf;
    int i0 = t;        { int ci = i0 / 9, k = i0 - ci * 9; w4s[k * 64 + ci] = w4r0; }
    int i1 = 256 + t;  { int ci = i1 / 9, k = i1 - ci * 9; w4s[k * 64 + ci] = w4r1; }
    if (t < 64) { int i2 = 512 + t; int ci = i2 / 9, k = i2 - ci * 9; w4s[k * 64 + ci] = w4r2; }
  }
  __syncthreads();

  // ======== conv4 (64->1) + bias + global max -> out[b] ========
  {
    const float* w4s = (const float*)s_buf;
    float val = -INFINITY;
    if (t < 81) {
      const int r = t / 9, c = t - (t / 9) * 9;
      float acc = 0.f;
      #pragma unroll
      for (int kr = 0; kr < 3; ++kr)
        #pragma unroll
        for (int kc = 0; kc < 3; ++kc) {
          const _Float16* ip = X3 + ((r + kr) * 16 + (c + kc)) * 72;
          const float* wk = w4s + (kr * 3 + kc) * 64;
          #pragma unroll
          for (int cig = 0; cig < 8; ++cig) {
            half8_t x = *(const half8_t*)(ip + cig * 8);
            #pragma unroll
            for (int j = 0; j < 8; ++j)
              acc = fmaf((float)x[j], wk[cig * 8 + j], acc);
          }
        }
      val = acc;
    }
    #pragma unroll
    for (int off = 32; off > 0; off >>= 1)
      val = fmaxf(val, __shfl_down(val, off, 64));
    if (lane == 0) s_red[wave] = val;
    __syncthreads();
    if (t == 0)
      out[b] = fmaxf(fmaxf(s_red[0], s_red[1]), fmaxf(s_red[2], s_red[3])) + c4b[0];
  }
}

// ---------------------------------------------------------------------------
extern "C" void kernel_launch(void* const* d_in, const int* in_sizes, int n_in,
                              void* d_out, int out_size, void* d_ws, size_t ws_size,
                              hipStream_t stream) {
  const float* ts   = (const float*)d_in[0];
  const float* ptm  = (const float*)d_in[1];
  const float* pmt  = (const float*)d_in[2];
  const float* piou = (const float*)d_in[3];
  const int*   mask = (const int*)d_in[4];
  const float* c1w = (const float*)d_in[5];
  const float* c1b = (const float*)d_in[6];
  const float* g1  = (const float*)d_in[7];
  const float* b1  = (const float*)d_in[8];
  const float* m1  = (const float*)d_in[9];
  const float* v1  = (const float*)d_in[10];
  const float* c2w = (const float*)d_in[11];
  const float* c2b = (const float*)d_in[12];
  const float* g2  = (const float*)d_in[13];
  const float* b2  = (const float*)d_in[14];
  const float* m2  = (const float*)d_in[15];
  const float* v2  = (const float*)d_in[16];
  const float* c3w = (const float*)d_in[17];
  const float* c3b = (const float*)d_in[18];
  const float* g3  = (const float*)d_in[19];
  const float* b3  = (const float*)d_in[20];
  const float* m3  = (const float*)d_in[21];
  const float* v3  = (const float*)d_in[22];
  const float* c4w = (const float*)d_in[23];
  const float* c4b = (const float*)d_in[24];

  char* ws = (char*)d_ws;
  _Float16*  img   = (_Float16*)ws;
  float*     scal  = (float*)(ws + OFF_SCAL);
  _Float16*  w2rep = (_Float16*)(ws + OFF_W2R);
  _Float16*  w3rep = (_Float16*)(ws + OFF_W3R);
  _Float16*  wr1   = (_Float16*)(ws + OFF_WR1);
  float*     wsum1 = (float*)(ws + OFF_WSUM1);

  k_stats<<<1850, 256, 0, stream>>>(
      ts, ptm, pmt, piou, mask, c1w, c2w, c3w,
      w2rep, w3rep, wr1, wsum1, img, scal);
  k_conv<<<NFB, 256, 0, stream>>>(
      img, scal, wr1, wsum1, c1b, g1, b1, m1, v1,
      w2rep, c2b, g2, b2, m2, v2,
      w3rep, c3b, g3, b3, m3, v3,
      c4w, c4b, (float*)d_out);
}